// Round 6
// baseline (114.596 us; speedup 1.0000x reference)
//
#include <hip/hip_runtime.h>

#define C_IN 64
#define C_OUT 16
#define H 256
#define W 256
#define HW 65536      // 256*256
#define N_B 8
#define L4 4096
#define L8 3969
#define L12 3844
#define LTOT 11909    // 4096 + 3969 + 3844
#define LDSP 260      // LDS row pitch in floats (256 data + 4 pad)

// native 16B vector (nontemporal load/store capable)
typedef float f4v __attribute__((ext_vector_type(4)));
// 2-byte-aligned ushort4 for unaligned bf16 row loads (element offset 4k-1)
typedef unsigned short us4a __attribute__((ext_vector_type(4), aligned(2)));

__device__ __forceinline__ void nt_store4(const float4& v, float* p) {
  f4v t; t.x = v.x; t.y = v.y; t.z = v.z; t.w = v.w;
  __builtin_nontemporal_store(t, reinterpret_cast<f4v*>(p));
}

// f32 -> bf16 (RNE) without header dependence
__device__ __forceinline__ unsigned short f2b(float f) {
  union { float f; unsigned u; } v; v.f = f;
  const unsigned r = v.u + 0x7FFFu + ((v.u >> 16) & 1u);
  return (unsigned short)(r >> 16);
}
__device__ __forceinline__ float b2f(unsigned short h) {
  union { unsigned u; float f; } v; v.u = ((unsigned)h) << 16;
  return v.f;
}

// load padded cols {4k-1..4k+2} of a bf16 row, clamping col -1 -> 0 (k==0)
__device__ __forceinline__ float4 load4cb(const unsigned short* __restrict__ row, int ws0) {
  if (ws0 >= 0) {
    us4a t = *reinterpret_cast<const us4a*>(row + ws0);
    return make_float4(b2f(t.x), b2f(t.y), b2f(t.z), b2f(t.w));
  }
  return make_float4(b2f(row[0]), b2f(row[0]), b2f(row[1]), b2f(row[2]));
}

// ---------------------------------------------------------------------------
// Stage 1: 1x1 conv 64->16 over the UNPADDED image; y stored as bf16.
// Each thread: 4 pixels (float4) x 16 outputs. Weights transposed in LDS.
// x loads are nontemporal (streamed once; keep L3 for y).
// ---------------------------------------------------------------------------
__global__ __launch_bounds__(256) void reduce_kernel(
    const float* __restrict__ x, const float* __restrict__ w,
    const float* __restrict__ b, unsigned short* __restrict__ y) {
  __shared__ float wt[C_IN][C_OUT];   // wt[c][o]
  for (int i = threadIdx.x; i < C_IN * C_OUT; i += 256)
    wt[i & 63][i >> 6] = w[i];        // w flat = o*64 + c
  __syncthreads();

  const unsigned gid = blockIdx.x * 256 + threadIdx.x;  // 131072 total
  const int n = gid >> 14;
  const int pix = (gid & 16383) << 2;
  const float* xp = x + (size_t)n * C_IN * HW + pix;

  float4 acc[C_OUT];
#pragma unroll
  for (int o = 0; o < C_OUT; ++o) {
    const float bv = b[o];
    acc[o] = make_float4(bv, bv, bv, bv);
  }

#define FMA4(A, WS) \
  A.x = fmaf(xv.x, WS, A.x); A.y = fmaf(xv.y, WS, A.y); \
  A.z = fmaf(xv.z, WS, A.z); A.w = fmaf(xv.w, WS, A.w);

#pragma unroll
  for (int c = 0; c < C_IN; ++c) {
    const f4v xv = __builtin_nontemporal_load(
        reinterpret_cast<const f4v*>(xp + (size_t)c * HW));
    const float4 w0 = *reinterpret_cast<const float4*>(&wt[c][0]);
    const float4 w1 = *reinterpret_cast<const float4*>(&wt[c][4]);
    const float4 w2 = *reinterpret_cast<const float4*>(&wt[c][8]);
    const float4 w3 = *reinterpret_cast<const float4*>(&wt[c][12]);
    FMA4(acc[0], w0.x)  FMA4(acc[1], w0.y)  FMA4(acc[2], w0.z)  FMA4(acc[3], w0.w)
    FMA4(acc[4], w1.x)  FMA4(acc[5], w1.y)  FMA4(acc[6], w1.z)  FMA4(acc[7], w1.w)
    FMA4(acc[8], w2.x)  FMA4(acc[9], w2.y)  FMA4(acc[10], w2.z) FMA4(acc[11], w2.w)
    FMA4(acc[12], w3.x) FMA4(acc[13], w3.y) FMA4(acc[14], w3.z) FMA4(acc[15], w3.w)
  }
#undef FMA4

  unsigned short* yp = y + (size_t)n * C_OUT * HW + pix;
#pragma unroll
  for (int o = 0; o < C_OUT; ++o) {
    us4a t;
    t.x = f2b(acc[o].x); t.y = f2b(acc[o].y);
    t.z = f2b(acc[o].z); t.w = f2b(acc[o].w);
    *reinterpret_cast<us4a*>(yp + (size_t)o * HW) = t;
  }
}

// ---------------------------------------------------------------------------
// Stage 2 (FUSED): block = (n, cq, oh in 0..63). Stage 12 clamp-padded bf16
// rows x 4 channels into an fp32 LDS tile:
//   lds[c][t][j] = y[clamp(oh*4+t-1)][clamp(j-1)]
// Then branch4 (bilinear, always), branch8 (copy, oh<63), branch12
// (adaptive avg, oh<62). Lane = (c:2, p:3, qh:1) -> wave stores 1KB runs.
// ---------------------------------------------------------------------------
__global__ __launch_bounds__(256) void patch_fused_kernel(
    const unsigned short* __restrict__ y, float* __restrict__ out) {
  const int CP = 12 * LDSP + 8;
  __shared__ float lds[4 * (12 * LDSP + 8)];   // 50,048 B
  const int bid = blockIdx.x;
  const int oh = bid & 63;
  const int cq = (bid >> 6) & 3;
  const int n = bid >> 8;
  const int tid = threadIdx.x;

  // ---- staging: 12 x 256 threads cover (c:4, t:12, k:64) ----
#pragma unroll
  for (int i = 0; i < 12; ++i) {
    const int sid = i * 256 + tid;
    const int c = sid / 768;
    const int rem = sid - c * 768;
    const int t = rem >> 6;
    const int k = rem & 63;
    const int r = min(max(oh * 4 + t - 1, 0), H - 1);
    const float4 v = load4cb(y + (size_t)(n * C_OUT + cq * 4 + c) * HW + (size_t)r * W, 4 * k - 1);
    *reinterpret_cast<float4*>(&lds[c * CP + t * LDSP + 4 * k]) = v;
  }
  __syncthreads();

  const int lane = tid & 63;
  const int c = lane >> 4;
  const int p = (lane >> 1) & 7;
  const int qh = lane & 1;
  const int lrow = tid >> 6;
  const float* lc = &lds[c * CP];
  const size_t obase = ((size_t)n * LTOT) * (C_OUT * 64) + (size_t)(cq * 4 + c) * 64 + p * 8 + qh * 4;

  // ---- branch 4: bilinear 4x4 -> 8x8 ----
  {
    const int ip0 = max(0, (p - 1) >> 1), ip1 = min(3, (p + 1) >> 1);
    const float wp0 = (p == 0 || p == 7) ? 1.0f : ((p & 1) ? 0.75f : 0.25f);
    const float wp1 = 1.0f - wp0;
    const float* lr0 = lc + ip0 * LDSP;
    const float* lr1 = lc + ip1 * LDSP;
    float* ob = out + obase + (size_t)(oh * 64) * (C_OUT * 64);

#pragma unroll
    for (int i = 0; i < 16; ++i) {
      const int ow = i * 4 + lrow;
      const float4 A = *reinterpret_cast<const float4*>(lr0 + ow * 4);
      const float4 B = *reinterpret_cast<const float4*>(lr1 + ow * 4);
      float4 ta, tb;
      if (qh == 0) {
        ta = make_float4(A.x, 0.75f * A.x + 0.25f * A.y, 0.25f * A.x + 0.75f * A.y, 0.75f * A.y + 0.25f * A.z);
        tb = make_float4(B.x, 0.75f * B.x + 0.25f * B.y, 0.25f * B.x + 0.75f * B.y, 0.75f * B.y + 0.25f * B.z);
      } else {
        ta = make_float4(0.25f * A.y + 0.75f * A.z, 0.75f * A.z + 0.25f * A.w, 0.25f * A.z + 0.75f * A.w, A.w);
        tb = make_float4(0.25f * B.y + 0.75f * B.z, 0.75f * B.z + 0.25f * B.w, 0.25f * B.z + 0.75f * B.w, B.w);
      }
      const float4 v = make_float4(wp0 * ta.x + wp1 * tb.x, wp0 * ta.y + wp1 * tb.y,
                                   wp0 * ta.z + wp1 * tb.z, wp0 * ta.w + wp1 * tb.w);
      nt_store4(v, ob + (size_t)ow * (C_OUT * 64));
    }
  }

  // ---- branch 8: identity copy ----
  if (oh < 63) {
    const float* lr = lc + p * LDSP + qh * 4;
    float* ob = out + obase + (size_t)(L4 + oh * 63) * (C_OUT * 64);
#pragma unroll
    for (int i = 0; i < 16; ++i) {
      const int ow = i * 4 + lrow;
      if (ow < 63) {
        const float4 v = *reinterpret_cast<const float4*>(lr + ow * 4);
        nt_store4(v, ob + (size_t)ow * (C_OUT * 64));
      }
    }
  }

  // ---- branch 12: adaptive avg 12 -> 8 (2x2 mean at a=(3p)>>1, b=(3q)>>1) ----
  if (oh < 62) {
    const int a = (3 * p) >> 1;
    const float* r0 = lc + a * LDSP;
    const float* r1 = r0 + LDSP;
    float* ob = out + obase + (size_t)(L4 + L8 + oh * 62) * (C_OUT * 64);
#pragma unroll
    for (int i = 0; i < 16; ++i) {
      const int ow = i * 4 + lrow;
      if (ow < 62) {
        // local cols qh*6..qh*6+5 of the 12-col window at ow*4:
        // F4 = b128 at ow*4 + qh*8, F2 = b64 at ow*4 + 4 + qh*2
        const float4 F40 = *reinterpret_cast<const float4*>(r0 + ow * 4 + qh * 8);
        const float2 F20 = *reinterpret_cast<const float2*>(r0 + ow * 4 + 4 + qh * 2);
        const float4 F41 = *reinterpret_cast<const float4*>(r1 + ow * 4 + qh * 8);
        const float2 F21 = *reinterpret_cast<const float2*>(r1 + ow * 4 + 4 + qh * 2);
        const float e0 = qh ? F20.x : F40.x, f0 = qh ? F21.x : F41.x;
        const float e1 = qh ? F20.y : F40.y, f1 = qh ? F21.y : F41.y;
        const float e2 = qh ? F40.x : F40.z, f2 = qh ? F41.x : F41.z;
        const float e3 = qh ? F40.y : F40.w, f3 = qh ? F41.y : F41.w;
        const float e4 = qh ? F40.z : F20.x, f4 = qh ? F41.z : F21.x;
        const float e5 = qh ? F40.w : F20.y, f5 = qh ? F41.w : F21.y;
        const float4 v = make_float4(0.25f * (e0 + e1 + f0 + f1),
                                     0.25f * (e1 + e2 + f1 + f2),
                                     0.25f * (e3 + e4 + f3 + f4),
                                     0.25f * (e4 + e5 + f4 + f5));
        nt_store4(v, ob + (size_t)ow * (C_OUT * 64));
      }
    }
  }
}

extern "C" void kernel_launch(void* const* d_in, const int* in_sizes, int n_in,
                              void* d_out, int out_size, void* d_ws, size_t ws_size,
                              hipStream_t stream) {
  const float* x = (const float*)d_in[0];
  const float* w = (const float*)d_in[1];
  const float* b = (const float*)d_in[2];
  float* out = (float*)d_out;
  unsigned short* y = (unsigned short*)d_ws;   // 8*16*256*256 bf16 = 16.8 MB

  reduce_kernel<<<512, 256, 0, stream>>>(x, w, b, y);
  patch_fused_kernel<<<N_B * 4 * 64, 256, 0, stream>>>(y, out);  // 2048 blocks
}

// Round 7
// 108.513 us; speedup vs baseline: 1.0561x; 1.0561x over previous
//
#include <hip/hip_runtime.h>

#define C_IN 64
#define C_OUT 16
#define H 256
#define W 256
#define HW 65536      // 256*256
#define N_B 8
#define L4 4096
#define L8 3969
#define L12 3844
#define LTOT 11909    // 4096 + 3969 + 3844
#define LDSP 260      // LDS row pitch in floats (256 data + 4 pad)

// native 16B vector (nontemporal store capable)
typedef float f4v __attribute__((ext_vector_type(4)));
// 2-byte-aligned ushort4 for unaligned bf16 row loads (element offset 4k-1)
typedef unsigned short us4a __attribute__((ext_vector_type(4), aligned(2)));

__device__ __forceinline__ void nt_store4(const float4& v, float* p) {
  f4v t; t.x = v.x; t.y = v.y; t.z = v.z; t.w = v.w;
  __builtin_nontemporal_store(t, reinterpret_cast<f4v*>(p));
}

// f32 -> bf16 (RNE) without header dependence
__device__ __forceinline__ unsigned short f2b(float f) {
  union { float f; unsigned u; } v; v.f = f;
  const unsigned r = v.u + 0x7FFFu + ((v.u >> 16) & 1u);
  return (unsigned short)(r >> 16);
}
__device__ __forceinline__ float b2f(unsigned short h) {
  union { unsigned u; float f; } v; v.u = ((unsigned)h) << 16;
  return v.f;
}

// load padded cols {4k-1..4k+2} of a bf16 row, clamping col -1 -> 0 (k==0)
__device__ __forceinline__ float4 load4cb(const unsigned short* __restrict__ row, int ws0) {
  if (ws0 >= 0) {
    us4a t = *reinterpret_cast<const us4a*>(row + ws0);
    return make_float4(b2f(t.x), b2f(t.y), b2f(t.z), b2f(t.w));
  }
  return make_float4(b2f(row[0]), b2f(row[0]), b2f(row[1]), b2f(row[2]));
}

// ---------------------------------------------------------------------------
// Stage 1: 1x1 conv 64->16 over the UNPADDED image; y stored as bf16.
// Each thread: 4 pixels (float4) x 16 outputs. Weights transposed in LDS.
// x loads are PLAIN (cache-resident x serves ~45% of fetches; NT forfeited
// that in R6 -> +5us). y stores normal (re-read by stage 2 via L2/L3).
// ---------------------------------------------------------------------------
__global__ __launch_bounds__(256) void reduce_kernel(
    const float* __restrict__ x, const float* __restrict__ w,
    const float* __restrict__ b, unsigned short* __restrict__ y) {
  __shared__ float wt[C_IN][C_OUT];   // wt[c][o]
  for (int i = threadIdx.x; i < C_IN * C_OUT; i += 256)
    wt[i & 63][i >> 6] = w[i];        // w flat = o*64 + c
  __syncthreads();

  const unsigned gid = blockIdx.x * 256 + threadIdx.x;  // 131072 total
  const int n = gid >> 14;
  const int pix = (gid & 16383) << 2;
  const float* xp = x + (size_t)n * C_IN * HW + pix;

  float4 acc[C_OUT];
#pragma unroll
  for (int o = 0; o < C_OUT; ++o) {
    const float bv = b[o];
    acc[o] = make_float4(bv, bv, bv, bv);
  }

#define FMA4(A, WS) \
  A.x = fmaf(xv.x, WS, A.x); A.y = fmaf(xv.y, WS, A.y); \
  A.z = fmaf(xv.z, WS, A.z); A.w = fmaf(xv.w, WS, A.w);

#pragma unroll
  for (int c = 0; c < C_IN; ++c) {
    const float4 xv = *reinterpret_cast<const float4*>(xp + (size_t)c * HW);
    const float4 w0 = *reinterpret_cast<const float4*>(&wt[c][0]);
    const float4 w1 = *reinterpret_cast<const float4*>(&wt[c][4]);
    const float4 w2 = *reinterpret_cast<const float4*>(&wt[c][8]);
    const float4 w3 = *reinterpret_cast<const float4*>(&wt[c][12]);
    FMA4(acc[0], w0.x)  FMA4(acc[1], w0.y)  FMA4(acc[2], w0.z)  FMA4(acc[3], w0.w)
    FMA4(acc[4], w1.x)  FMA4(acc[5], w1.y)  FMA4(acc[6], w1.z)  FMA4(acc[7], w1.w)
    FMA4(acc[8], w2.x)  FMA4(acc[9], w2.y)  FMA4(acc[10], w2.z) FMA4(acc[11], w2.w)
    FMA4(acc[12], w3.x) FMA4(acc[13], w3.y) FMA4(acc[14], w3.z) FMA4(acc[15], w3.w)
  }
#undef FMA4

  unsigned short* yp = y + (size_t)n * C_OUT * HW + pix;
#pragma unroll
  for (int o = 0; o < C_OUT; ++o) {
    us4a t;
    t.x = f2b(acc[o].x); t.y = f2b(acc[o].y);
    t.z = f2b(acc[o].z); t.w = f2b(acc[o].w);
    *reinterpret_cast<us4a*>(yp + (size_t)o * HW) = t;
  }
}

// ---------------------------------------------------------------------------
// Stage 2 (FUSED): block = (n, cq, oh in 0..63). Stage 12 clamp-padded bf16
// rows x 4 channels into an fp32 LDS tile:
//   lds[c][t][j] = y[clamp(oh*4+t-1)][clamp(j-1)]
// Then branch4 (bilinear, always), branch8 (copy, oh<63), branch12
// (adaptive avg, oh<62). Lane = (c:2, p:3, qh:1) -> wave stores 1KB runs.
// ---------------------------------------------------------------------------
__global__ __launch_bounds__(256) void patch_fused_kernel(
    const unsigned short* __restrict__ y, float* __restrict__ out) {
  const int CP = 12 * LDSP + 8;
  __shared__ float lds[4 * (12 * LDSP + 8)];   // 50,048 B
  const int bid = blockIdx.x;
  const int oh = bid & 63;
  const int cq = (bid >> 6) & 3;
  const int n = bid >> 8;
  const int tid = threadIdx.x;

  // ---- staging: 12 x 256 threads cover (c:4, t:12, k:64) ----
#pragma unroll
  for (int i = 0; i < 12; ++i) {
    const int sid = i * 256 + tid;
    const int c = sid / 768;
    const int rem = sid - c * 768;
    const int t = rem >> 6;
    const int k = rem & 63;
    const int r = min(max(oh * 4 + t - 1, 0), H - 1);
    const float4 v = load4cb(y + (size_t)(n * C_OUT + cq * 4 + c) * HW + (size_t)r * W, 4 * k - 1);
    *reinterpret_cast<float4*>(&lds[c * CP + t * LDSP + 4 * k]) = v;
  }
  __syncthreads();

  const int lane = tid & 63;
  const int c = lane >> 4;
  const int p = (lane >> 1) & 7;
  const int qh = lane & 1;
  const int lrow = tid >> 6;
  const float* lc = &lds[c * CP];
  const size_t obase = ((size_t)n * LTOT) * (C_OUT * 64) + (size_t)(cq * 4 + c) * 64 + p * 8 + qh * 4;

  // ---- branch 4: bilinear 4x4 -> 8x8 ----
  {
    const int ip0 = max(0, (p - 1) >> 1), ip1 = min(3, (p + 1) >> 1);
    const float wp0 = (p == 0 || p == 7) ? 1.0f : ((p & 1) ? 0.75f : 0.25f);
    const float wp1 = 1.0f - wp0;
    const float* lr0 = lc + ip0 * LDSP;
    const float* lr1 = lc + ip1 * LDSP;
    float* ob = out + obase + (size_t)(oh * 64) * (C_OUT * 64);

#pragma unroll
    for (int i = 0; i < 16; ++i) {
      const int ow = i * 4 + lrow;
      const float4 A = *reinterpret_cast<const float4*>(lr0 + ow * 4);
      const float4 B = *reinterpret_cast<const float4*>(lr1 + ow * 4);
      float4 ta, tb;
      if (qh == 0) {
        ta = make_float4(A.x, 0.75f * A.x + 0.25f * A.y, 0.25f * A.x + 0.75f * A.y, 0.75f * A.y + 0.25f * A.z);
        tb = make_float4(B.x, 0.75f * B.x + 0.25f * B.y, 0.25f * B.x + 0.75f * B.y, 0.75f * B.y + 0.25f * B.z);
      } else {
        ta = make_float4(0.25f * A.y + 0.75f * A.z, 0.75f * A.z + 0.25f * A.w, 0.25f * A.z + 0.75f * A.w, A.w);
        tb = make_float4(0.25f * B.y + 0.75f * B.z, 0.75f * B.z + 0.25f * B.w, 0.25f * B.z + 0.75f * B.w, B.w);
      }
      const float4 v = make_float4(wp0 * ta.x + wp1 * tb.x, wp0 * ta.y + wp1 * tb.y,
                                   wp0 * ta.z + wp1 * tb.z, wp0 * ta.w + wp1 * tb.w);
      nt_store4(v, ob + (size_t)ow * (C_OUT * 64));
    }
  }

  // ---- branch 8: identity copy ----
  if (oh < 63) {
    const float* lr = lc + p * LDSP + qh * 4;
    float* ob = out + obase + (size_t)(L4 + oh * 63) * (C_OUT * 64);
#pragma unroll
    for (int i = 0; i < 16; ++i) {
      const int ow = i * 4 + lrow;
      if (ow < 63) {
        const float4 v = *reinterpret_cast<const float4*>(lr + ow * 4);
        nt_store4(v, ob + (size_t)ow * (C_OUT * 64));
      }
    }
  }

  // ---- branch 12: adaptive avg 12 -> 8 (2x2 mean at a=(3p)>>1, b=(3q)>>1) ----
  if (oh < 62) {
    const int a = (3 * p) >> 1;
    const float* r0 = lc + a * LDSP;
    const float* r1 = r0 + LDSP;
    float* ob = out + obase + (size_t)(L4 + L8 + oh * 62) * (C_OUT * 64);
#pragma unroll
    for (int i = 0; i < 16; ++i) {
      const int ow = i * 4 + lrow;
      if (ow < 62) {
        // local cols qh*6..qh*6+5 of the 12-col window at ow*4:
        // F4 = b128 at ow*4 + qh*8, F2 = b64 at ow*4 + 4 + qh*2
        const float4 F40 = *reinterpret_cast<const float4*>(r0 + ow * 4 + qh * 8);
        const float2 F20 = *reinterpret_cast<const float2*>(r0 + ow * 4 + 4 + qh * 2);
        const float4 F41 = *reinterpret_cast<const float4*>(r1 + ow * 4 + qh * 8);
        const float2 F21 = *reinterpret_cast<const float2*>(r1 + ow * 4 + 4 + qh * 2);
        const float e0 = qh ? F20.x : F40.x, f0 = qh ? F21.x : F41.x;
        const float e1 = qh ? F20.y : F40.y, f1 = qh ? F21.y : F41.y;
        const float e2 = qh ? F40.x : F40.z, f2 = qh ? F41.x : F41.z;
        const float e3 = qh ? F40.y : F40.w, f3 = qh ? F41.y : F41.w;
        const float e4 = qh ? F40.z : F20.x, f4 = qh ? F41.z : F21.x;
        const float e5 = qh ? F40.w : F20.y, f5 = qh ? F41.w : F21.y;
        const float4 v = make_float4(0.25f * (e0 + e1 + f0 + f1),
                                     0.25f * (e1 + e2 + f1 + f2),
                                     0.25f * (e3 + e4 + f3 + f4),
                                     0.25f * (e4 + e5 + f4 + f5));
        nt_store4(v, ob + (size_t)ow * (C_OUT * 64));
      }
    }
  }
}

extern "C" void kernel_launch(void* const* d_in, const int* in_sizes, int n_in,
                              void* d_out, int out_size, void* d_ws, size_t ws_size,
                              hipStream_t stream) {
  const float* x = (const float*)d_in[0];
  const float* w = (const float*)d_in[1];
  const float* b = (const float*)d_in[2];
  float* out = (float*)d_out;
  unsigned short* y = (unsigned short*)d_ws;   // 8*16*256*256 bf16 = 16.8 MB

  reduce_kernel<<<512, 256, 0, stream>>>(x, w, b, y);
  patch_fused_kernel<<<N_B * 4 * 64, 256, 0, stream>>>(y, out);  // 2048 blocks
}

// Round 9
// 107.139 us; speedup vs baseline: 1.0696x; 1.0128x over previous
//
#include <hip/hip_runtime.h>

#define C_IN 64
#define C_OUT 16
#define H 256
#define W 256
#define HW 65536      // 256*256
#define N_B 8
#define L4 4096
#define L8 3969
#define L12 3844
#define LTOT 11909    // 4096 + 3969 + 3844
#define LDSP 260      // LDS row pitch in floats

// native 16B vector (nontemporal store capable)
typedef float f4v __attribute__((ext_vector_type(4)));
// 8 bf16 = 16B aligned staging load
typedef unsigned short us8 __attribute__((ext_vector_type(8)));
// bf16x4 for y stores in stage 1
typedef unsigned short us4 __attribute__((ext_vector_type(4)));

__device__ __forceinline__ void nt_store4(const float4& v, float* p) {
  f4v t; t.x = v.x; t.y = v.y; t.z = v.z; t.w = v.w;
  __builtin_nontemporal_store(t, reinterpret_cast<f4v*>(p));
}

// f32 -> bf16 (RNE) without header dependence
__device__ __forceinline__ unsigned short f2b(float f) {
  union { float f; unsigned u; } v; v.f = f;
  const unsigned r = v.u + 0x7FFFu + ((v.u >> 16) & 1u);
  return (unsigned short)(r >> 16);
}
__device__ __forceinline__ float b2f(unsigned short h) {
  union { unsigned u; float f; } v; v.u = ((unsigned)h) << 16;
  return v.f;
}

// ---------------------------------------------------------------------------
// Stage 1: 1x1 conv 64->16 over the UNPADDED image; y stored as bf16.
// Each thread: 4 pixels (float4) x 16 outputs. Weights transposed in LDS.
// Plain x loads (cache-resident x serves ~45% of fetches; NT hurt in R6).
// ---------------------------------------------------------------------------
__global__ __launch_bounds__(256) void reduce_kernel(
    const float* __restrict__ x, const float* __restrict__ w,
    const float* __restrict__ b, unsigned short* __restrict__ y) {
  __shared__ float wt[C_IN][C_OUT];   // wt[c][o]
  for (int i = threadIdx.x; i < C_IN * C_OUT; i += 256)
    wt[i & 63][i >> 6] = w[i];        // w flat = o*64 + c
  __syncthreads();

  const unsigned gid = blockIdx.x * 256 + threadIdx.x;  // 131072 total
  const int n = gid >> 14;
  const int pix = (gid & 16383) << 2;
  const float* xp = x + (size_t)n * C_IN * HW + pix;

  float4 acc[C_OUT];
#pragma unroll
  for (int o = 0; o < C_OUT; ++o) {
    const float bv = b[o];
    acc[o] = make_float4(bv, bv, bv, bv);
  }

#define FMA4(A, WS) \
  A.x = fmaf(xv.x, WS, A.x); A.y = fmaf(xv.y, WS, A.y); \
  A.z = fmaf(xv.z, WS, A.z); A.w = fmaf(xv.w, WS, A.w);

#pragma unroll
  for (int c = 0; c < C_IN; ++c) {
    const float4 xv = *reinterpret_cast<const float4*>(xp + (size_t)c * HW);
    const float4 w0 = *reinterpret_cast<const float4*>(&wt[c][0]);
    const float4 w1 = *reinterpret_cast<const float4*>(&wt[c][4]);
    const float4 w2 = *reinterpret_cast<const float4*>(&wt[c][8]);
    const float4 w3 = *reinterpret_cast<const float4*>(&wt[c][12]);
    FMA4(acc[0], w0.x)  FMA4(acc[1], w0.y)  FMA4(acc[2], w0.z)  FMA4(acc[3], w0.w)
    FMA4(acc[4], w1.x)  FMA4(acc[5], w1.y)  FMA4(acc[6], w1.z)  FMA4(acc[7], w1.w)
    FMA4(acc[8], w2.x)  FMA4(acc[9], w2.y)  FMA4(acc[10], w2.z) FMA4(acc[11], w2.w)
    FMA4(acc[12], w3.x) FMA4(acc[13], w3.y) FMA4(acc[14], w3.z) FMA4(acc[15], w3.w)
  }
#undef FMA4

  unsigned short* yp = y + (size_t)n * C_OUT * HW + pix;
#pragma unroll
  for (int o = 0; o < C_OUT; ++o) {
    us4 t;
    t.x = f2b(acc[o].x); t.y = f2b(acc[o].y);
    t.z = f2b(acc[o].z); t.w = f2b(acc[o].w);
    *reinterpret_cast<us4*>(yp + (size_t)o * HW) = t;
  }
}

// ---------------------------------------------------------------------------
// Stage 2 (FUSED): block = (n, ch-pair cp, oh-pair j). Stage 16 clamp-padded
// rows x 2 channels with ALIGNED us8 loads; shift (+1 elem) happens on the
// LDS-write side. Tile element m of a row holds y[clamp(m-1)]. The ch==0
// stager ALSO writes element 0 (= y col 0) from its own register — the R8
// version did this via a cross-wave LDS read before the barrier (race).
// Emits oh = 2j and 2j+1: branch4 (always), branch8 (oh<63), branch12 (oh<62).
// Lane = (z:1)(c:1)(p:3)(qh:1) -> lanes 0..31 / 32..63 each cover 512B runs.
// ---------------------------------------------------------------------------
__global__ __launch_bounds__(256) void patch_fused_kernel(
    const unsigned short* __restrict__ y, float* __restrict__ out) {
  const int CP = 16 * LDSP + 8;
  __shared__ float lds[2 * (16 * LDSP + 8)];   // 33,344 B -> 4 blocks/CU
  const int bid = blockIdx.x;
  const int j  = bid & 31;          // oh-pair: oh = 2j, 2j+1
  const int cp = (bid >> 5) & 7;    // channel pair
  const int n  = bid >> 8;
  const int tid = threadIdx.x;

  // ---- staging: 4 passes cover (c:2, row:16, chunk:32); 16B-aligned loads
#pragma unroll
  for (int pass = 0; pass < 4; ++pass) {
    const int sid = pass * 256 + tid;
    const int c  = sid >> 9;
    const int tp = (sid >> 5) & 15;
    const int ch = sid & 31;
    const int r = min(max(8 * j + tp - 1, 0), H - 1);
    const us8 v = *reinterpret_cast<const us8*>(
        y + (size_t)(n * C_OUT + cp * 2 + c) * HW + (size_t)r * W + ch * 8);
    float* d = &lds[c * CP + tp * LDSP + ch * 8 + 1];
#pragma unroll
    for (int e = 0; e < 8; ++e) d[e] = b2f(v[e]);
    if (ch == 0) d[-1] = b2f(v.x);   // left clamp from own register (no race)
  }
  __syncthreads();

  const int lane = tid & 63;
  const int z  = lane >> 5;          // ow low bit
  const int c  = (lane >> 4) & 1;
  const int p  = (lane >> 1) & 7;
  const int qh = lane & 1;
  const int lrow = tid >> 6;         // wave id 0..3
  const float* lc = &lds[c * CP];
  const size_t obase0 = ((size_t)n * LTOT) * (C_OUT * 64)
                        + (size_t)(cp * 2 + c) * 64 + p * 8 + qh * 4;

#pragma unroll
  for (int sub = 0; sub < 2; ++sub) {
    const int oh = 2 * j + sub;
    const int rb = sub * 4;          // tile-row base for this oh

    // ---- branch 4: bilinear 4x4 -> 8x8 ----
    {
      const int ip0 = max(0, (p - 1) >> 1), ip1 = min(3, (p + 1) >> 1);
      const float wp0 = (p == 0 || p == 7) ? 1.0f : ((p & 1) ? 0.75f : 0.25f);
      const float wp1 = 1.0f - wp0;
      const float* lr0 = lc + (rb + ip0) * LDSP;
      const float* lr1 = lc + (rb + ip1) * LDSP;
      float* ob = out + obase0 + (size_t)(oh * 64) * (C_OUT * 64);
#pragma unroll
      for (int i = 0; i < 8; ++i) {
        const int ow = i * 8 + lrow * 2 + z;
        const float4 A = *reinterpret_cast<const float4*>(lr0 + ow * 4);
        const float4 B = *reinterpret_cast<const float4*>(lr1 + ow * 4);
        float4 ta, tb;
        if (qh == 0) {
          ta = make_float4(A.x, 0.75f * A.x + 0.25f * A.y, 0.25f * A.x + 0.75f * A.y, 0.75f * A.y + 0.25f * A.z);
          tb = make_float4(B.x, 0.75f * B.x + 0.25f * B.y, 0.25f * B.x + 0.75f * B.y, 0.75f * B.y + 0.25f * B.z);
        } else {
          ta = make_float4(0.25f * A.y + 0.75f * A.z, 0.75f * A.z + 0.25f * A.w, 0.25f * A.z + 0.75f * A.w, A.w);
          tb = make_float4(0.25f * B.y + 0.75f * B.z, 0.75f * B.z + 0.25f * B.w, 0.25f * B.z + 0.75f * B.w, B.w);
        }
        const float4 v = make_float4(wp0 * ta.x + wp1 * tb.x, wp0 * ta.y + wp1 * tb.y,
                                     wp0 * ta.z + wp1 * tb.z, wp0 * ta.w + wp1 * tb.w);
        nt_store4(v, ob + (size_t)ow * (C_OUT * 64));
      }
    }

    // ---- branch 8: identity copy ----
    if (oh < 63) {
      const float* lr = lc + (rb + p) * LDSP + qh * 4;
      float* ob = out + obase0 + (size_t)(L4 + oh * 63) * (C_OUT * 64);
#pragma unroll
      for (int i = 0; i < 8; ++i) {
        const int ow = i * 8 + lrow * 2 + z;
        if (ow < 63) {
          const float4 v = *reinterpret_cast<const float4*>(lr + ow * 4);
          nt_store4(v, ob + (size_t)ow * (C_OUT * 64));
        }
      }
    }

    // ---- branch 12: adaptive avg 12 -> 8 (2x2 mean at a=(3p)>>1) ----
    if (oh < 62) {
      const int a = (3 * p) >> 1;
      const float* r0 = lc + (rb + a) * LDSP;
      const float* r1 = r0 + LDSP;
      float* ob = out + obase0 + (size_t)(L4 + L8 + oh * 62) * (C_OUT * 64);
#pragma unroll
      for (int i = 0; i < 8; ++i) {
        const int ow = i * 8 + lrow * 2 + z;
        if (ow < 62) {
          // local cols qh*6..qh*6+5 of the 12-col window at ow*4:
          // F4 = b128 at ow*4 + qh*8, F2 = b64 at ow*4 + 4 + qh*2
          const float4 F40 = *reinterpret_cast<const float4*>(r0 + ow * 4 + qh * 8);
          const float2 F20 = *reinterpret_cast<const float2*>(r0 + ow * 4 + 4 + qh * 2);
          const float4 F41 = *reinterpret_cast<const float4*>(r1 + ow * 4 + qh * 8);
          const float2 F21 = *reinterpret_cast<const float2*>(r1 + ow * 4 + 4 + qh * 2);
          const float e0 = qh ? F20.x : F40.x, f0 = qh ? F21.x : F41.x;
          const float e1 = qh ? F20.y : F40.y, f1 = qh ? F21.y : F41.y;
          const float e2 = qh ? F40.x : F40.z, f2 = qh ? F41.x : F41.z;
          const float e3 = qh ? F40.y : F40.w, f3 = qh ? F41.y : F41.w;
          const float e4 = qh ? F40.z : F20.x, f4 = qh ? F41.z : F21.x;
          const float e5 = qh ? F40.w : F20.y, f5 = qh ? F41.w : F21.y;
          const float4 v = make_float4(0.25f * (e0 + e1 + f0 + f1),
                                       0.25f * (e1 + e2 + f1 + f2),
                                       0.25f * (e3 + e4 + f3 + f4),
                                       0.25f * (e4 + e5 + f4 + f5));
          nt_store4(v, ob + (size_t)ow * (C_OUT * 64));
        }
      }
    }
  }
}

extern "C" void kernel_launch(void* const* d_in, const int* in_sizes, int n_in,
                              void* d_out, int out_size, void* d_ws, size_t ws_size,
                              hipStream_t stream) {
  const float* x = (const float*)d_in[0];
  const float* w = (const float*)d_in[1];
  const float* b = (const float*)d_in[2];
  float* out = (float*)d_out;
  unsigned short* y = (unsigned short*)d_ws;   // 8*16*256*256 bf16 = 16.8 MB

  reduce_kernel<<<512, 256, 0, stream>>>(x, w, b, y);
  patch_fused_kernel<<<N_B * 8 * 32, 256, 0, stream>>>(y, out);  // 2048 blocks
}